// Round 10
// baseline (382.391 us; speedup 1.0000x reference)
//
#include <hip/hip_runtime.h>
#include <math.h>

#define Bb 4
#define Mm 8192
#define Kk 64
#define Cc 32
#define Pp 28

#define OFF_PSDF  (Bb*Mm)                          // 32768
#define OFF_INTER (Bb*Mm + Bb*Mm*Kk)               // 2129920
#define OFF_SD    (Bb*Mm + Bb*Mm*Kk + Bb*Mm*Cc)    // 3178496

#define W40    57.707801635558535f      // 40*log2(e)
#define NL2_40 (-0.017328679513998632f) // -ln2/40
#define S75    108.20212806667225f      // 75*log2(e)
#define EPS_OCC 1e-6f

struct Rad12 { float v[12]; };

__device__ __forceinline__ float fexp2(float x){ return __builtin_amdgcn_exp2f(x); }
__device__ __forceinline__ float frcp(float x){ return __builtin_amdgcn_rcpf(x); }

// ---------------- Kernel 0: expand curves + params + (k,c) sums ------------
// thread g -> k = g&63 (coalesced), n = (g>>6)&63, b = g>>12
// ws_c [b][j=n>>1][k][4] = {m2x_e, m2x_o, m2y_e, m2y_o}
__global__ __launch_bounds__(256)
void curve_prep(const float* __restrict__ pp, const float* __restrict__ iw_g,
                Rad12 rad,
                float* __restrict__ ws_c, float* __restrict__ params_ws,
                float2* __restrict__ st_ws)
{
    const int g = blockIdx.x * 256 + threadIdx.x;   // 16384 threads
    const int k = g & 63;
    const int n = (g >> 6) & 63;
    const int b = g >> 12;

#define PP(p) pp[((b * Pp) + (p)) * Kk + k]

    const int s  = n >> 4;
    const int it = n & 15;
    const float t = (float)it * 0.0625f;            // exact i/16
    const int s1 = (s + 1) & 3;

    float r0 = fabsf(PP(8 + 3 * s + 0));
    float r1 = fabsf(PP(8 + 3 * s + 1));
    float r2 = fabsf(PP(8 + 3 * s + 2));
    float r3 = fabsf(PP(8 + 3 * s1 + 0));
    float w1 = fabsf(PP(20 + 2 * s + 0));
    float w2 = fabsf(PP(20 + 2 * s + 1));

    float a0 = rad.v[3 * s + 0], a1 = rad.v[3 * s + 1];
    float a2 = rad.v[3 * s + 2], a3 = rad.v[3 * s1 + 0];

    float P0x = cosf(a0) * r0, P0y = sinf(a0) * r0;
    float P1x = cosf(a1) * r1, P1y = sinf(a1) * r1;
    float P2x = cosf(a2) * r2, P2y = sinf(a2) * r2;
    float P3x = cosf(a3) * r3, P3y = sinf(a3) * r3;

    float omt = 1.0f - t;
    float b0 = omt * omt * omt;
    float b1 = (3.0f * t) * (omt * omt);
    float b2 = (3.0f * (t * t)) * omt;
    float b3 = t * t * t;
    float bw1 = b1 * w1, bw2 = b2 * w2;
    float den = ((b0 + bw1) + bw2) + b3;
    float nx  = ((b0 * P0x + bw1 * P1x) + bw2 * P2x) + b3 * P3x;
    float ny  = ((b0 * P0y + bw1 * P1y) + bw2 * P2y) + b3 * P3y;

    float cx = nx / den, cy = ny / den;
    const int j = n >> 1, h = n & 1;
    float* base = ws_c + (((b * 32 + j) * 64) + k) * 4;
    base[h]     = -2.0f * cx;
    base[2 + h] = -2.0f * cy;

    if (n < 8) {
        float val;
        if (n < 4) {
            float q0 = PP(0), q1 = PP(1), q2 = PP(2), q3 = PP(3);
            float nrm = sqrtf(q0 * q0 + q1 * q1 + q2 * q2 + q3 * q3);
            val = PP(n) / nrm;
        } else {
            val = PP(n);        // p=4..6 trans, p=7 height
        }
        params_ws[(b * Kk + k) * 8 + n] = val;
    }
#undef PP

    // fold-in: per-(b,c) saturated-occ softmin sums S0,T0
    if (blockIdx.x == 0 && threadIdx.x < 128) {
        const int tb = threadIdx.x >> 5, tc = threadIdx.x & 31;
        float S = 0.0f, T = 0.0f;
        for (int kk = 0; kk < 64; ++kk) {
            float w   = iw_g[tb * 2048 + kk * 32 + tc];
            float b40 = (w - 1.0f) * W40;
            float e   = fexp2(b40);
            S += e;
            T  = fmaf(e, b40, T);
        }
        st_ws[threadIdx.x] = make_float2(S, T);
    }
}

// ---------------- Kernel 1: fused main ------------------------------------
// block = 512 threads = 8 waves; each wave = 4 points (ph1 lane = primitive k).
// LDS pool 8256 floats = 33 KB -> 4 blocks/CU; grid 1024 = 256 CU x 4: ONE round.
//   ph1: [0,8192) curve quads [j][k][4]   (csq recomputed in-register, 4x-scaled)
//   ph2 (aliased after barrier): [0,2048) occ [ptl][k];
//        [2048,6144) float2 {a,b} tables [k][c]
//   [8192,8256) S0T0 float2[c]  (non-aliased)
__global__ __launch_bounds__(512, 8)
void csg_main(const float* __restrict__ pts, const float* __restrict__ iw_g,
              const float* __restrict__ uw_g, const int* __restrict__ flag,
              const float* __restrict__ ws_c, const float* __restrict__ params_ws,
              const float2* __restrict__ st_ws, float* __restrict__ out)
{
    __shared__ __align__(16) float s_pool[8256];

    const int tid = threadIdx.x;
    const int bid = blockIdx.x;
    const int b   = bid >> 8;                  // 256 blocks per batch
    const int m0  = (bid & 255) << 5;          // 32 points per block

    // ---- stage LDS (curve quads) + iw into regs ----
    float wreg[4];
    {
        const float4* cs = (const float4*)(ws_c + (size_t)b * 8192);
        float4* cd = (float4*)s_pool;
#pragma unroll
        for (int i = 0; i < 4; ++i) cd[tid + i * 512] = cs[tid + i * 512];
#pragma unroll
        for (int i = 0; i < 4; ++i) wreg[i] = iw_g[b * 2048 + tid + i * 512];
        if (tid < 32) ((float2*)&s_pool[8192])[tid] = st_ws[b * 32 + tid];
    }
    __syncthreads();

    const int wid  = tid >> 6;
    const int lane = tid & 63;
    const int k    = lane;
    const int pt0  = b * Mm + m0 + (wid << 2);   // 4 pts per wave

    const float4* prm4 = (const float4*)(params_ws + ((b << 6) + k) * 8);
    float4 q4 = prm4[0];   // qw qx qy qz (normalized)
    float4 t4 = prm4[1];   // tx ty tz height

    const float4* pts4 = (const float4*)(pts + (size_t)pt0 * 3);
    float4 A = pts4[0], Bv = pts4[1], Cv = pts4[2];
    float pxs[4] = {A.x, A.w, Bv.z, Cv.y};
    float pys[4] = {A.y, Bv.x, Bv.w, Cv.z};
    float pzs[4] = {A.z, Bv.y, Cv.x, Cv.w};

    float px4[4], py4[4], plzv[4], psq[4];
    {
        float vx = -q4.y, vy = -q4.z, vz = -q4.w, qw = q4.x;
#pragma unroll
        for (int p = 0; p < 4; ++p) {
            float px = pxs[p] - t4.x, py = pys[p] - t4.y, pz = pzs[p] - t4.z;
            float t1x = 2.0f * (vy * pz - vz * py);
            float t1y = 2.0f * (vz * px - vx * pz);
            float t1z = 2.0f * (vx * py - vy * px);
            float plx = px + qw * t1x + (vy * t1z - vz * t1y);
            float ply = py + qw * t1y + (vz * t1x - vx * t1z);
            plzv[p] = pz + qw * t1z + (vx * t1y - vy * t1x);
            psq[p]  = plx * plx + ply * ply;
            px4[p]  = 4.0f * plx;                 // exact pow2 scale
            py4[p]  = 4.0f * ply;
        }
    }

    // 4x-scaled: cq4 = 4*csq = fma(m2x,m2x,m2y^2) exact;
    // d4 = 4*(csq - 2*dot) = fma(m2x, 4px, fma(m2y, 4py, cq4)) exact.
    // strict-< argmin identical; d2 = psq + 0.25*best4 exact.
    float best4[4] = {1e30f, 1e30f, 1e30f, 1e30f};
    float bcsq4[4] = {0.0f, 0.0f, 0.0f, 0.0f};
    {
        const float4* cdp = (const float4*)&s_pool[k * 4];   // j*1024B imm
#pragma unroll
        for (int j = 0; j < 32; ++j) {
            float4 cd = cdp[j * 64];       // {m2x_e, m2x_o, m2y_e, m2y_o}
            float cq4x = fmaf(cd.x, cd.x, cd.z * cd.z);
            float cq4y = fmaf(cd.y, cd.y, cd.w * cd.w);
#pragma unroll
            for (int p = 0; p < 4; ++p) {
                float da = fmaf(cd.x, px4[p], fmaf(cd.z, py4[p], cq4x));
                if (da < best4[p]) { best4[p] = da; bcsq4[p] = cq4x; }
                float db = fmaf(cd.y, px4[p], fmaf(cd.w, py4[p], cq4y));
                if (db < best4[p]) { best4[p] = db; bcsq4[p] = cq4y; }
            }
        }
    }

    float occ[4];
    unsigned long long mask[4];
#pragma unroll
    for (int p = 0; p < 4; ++p) {
        float d2    = psq[p] + 0.25f * best4[p];        // == psq + best exact
        float bq    = 0.25f * bcsq4[p];                 // == bcsq exact
        float ud    = sqrtf(fmaxf(d2, 0.0f) + 1e-12f);
        float sgn   = (psq[p] <= bq) ? -1.0f : 1.0f;    // == sqrt-compare
        float sdf2d = sgn * ud;
        float dzv   = fabsf(plzv[p]) - t4.w;
        float inner = fminf(fmaxf(sdf2d, dzv), 0.0f);
        float r1m   = fmaxf(sdf2d, 0.0f), r2m = fmaxf(dzv, 0.0f);
        float psdf  = inner + sqrtf(r1m * r1m + r2m * r2m + 1e-12f);
        out[OFF_PSDF + (pt0 + p) * Kk + k] = psdf;
        out[OFF_SD   + (pt0 + p) * Kk + k] = ud;
        occ[p]  = frcp(1.0f + fexp2(S75 * psdf));   // sigmoid(-75*psdf)
        mask[p] = __ballot(occ[p] > EPS_OCC);
    }

    // ---- barrier: curve LDS dead; build ph2 tables ----
    __syncthreads();
    {
        const int ptl = wid << 2;
#pragma unroll
        for (int p = 0; p < 4; ++p)
            s_pool[(ptl + p) * 64 + k] = occ[p];
#pragma unroll
        for (int i = 0; i < 4; ++i) {
            int idx = tid + i * 512;               // (k,c) = idx>>5, idx&31
            float w = wreg[i];
            ((float2*)&s_pool[2048])[idx] = make_float2(w * (-W40), (w - 1.0f) * W40);
        }
    }
    __syncthreads();

    // ================= Phase 2: lane = c (duplicated across halves) ========
    const int training = flag[0];
    const int c = lane & 31;
    const float2* tbl = (const float2*)&s_pool[2048];

    float inter[4];
    if (training) {
        float2 s0t0 = ((const float2*)&s_pool[8192])[c];
#pragma unroll
        for (int p = 0; p < 4; ++p) {
            unsigned long long m = mask[p];
            const int ptl = (wid << 2) + p;
            float sw = s0t0.x, swp = s0t0.y;
            while (m) {
                int kk = __builtin_ctzll(m); m &= m - 1;
                float osv = s_pool[ptl * 64 + kk];          // broadcast
                float2 wv = tbl[kk * 32 + c];               // {a, b}
                float pre = fmaf(wv.x, osv, wv.y);          // -40*log2e*pre_i
                float e   = fexp2(pre);                     // in (0,1]: safe
                float e0  = fexp2(wv.y);                    // saturated term
                sw  += (e - e0);
                swp += fmaf(e, pre, -(e0 * wv.y));
            }
            inter[p] = swp * frcp(sw) * NL2_40;
        }
    } else {
#pragma unroll
        for (int p = 0; p < 4; ++p) {
            const int ptl = (wid << 2) + p;
            float mx = -1e30f;
            for (int kk = 0; kk < 64; ++kk) {
                float osv = s_pool[ptl * 64 + kk];
                float2 wv = tbl[kk * 32 + c];
                mx = fmaxf(mx, fmaf(wv.x, osv, wv.y));
            }
            inter[p] = mx * NL2_40;                 // min_k pre_i
        }
    }

    if (lane < Cc) {
#pragma unroll
        for (int p = 0; p < 4; ++p)
            out[OFF_INTER + (pt0 + p) * Cc + c] = inter[p];
    }

    // ---- union over c (softmax / max) ----
    float uwv = uw_g[b * Cc + c];
    float resv[4];
    if (training) {
#pragma unroll
        for (int p = 0; p < 4; ++p) {
            float pu  = uwv * inter[p];
            float e   = fexp2(W40 * pu);             // exp(40*pre_u) <= e^40
            float num = e * pu, den = e;
#pragma unroll
            for (int msk = 16; msk >= 1; msk >>= 1) {
                num += __shfl_xor(num, msk, 64);
                den += __shfl_xor(den, msk, 64);
            }
            resv[p] = num * frcp(den);
        }
    } else {
#pragma unroll
        for (int p = 0; p < 4; ++p) {
            float pu = uwv * inter[p];
#pragma unroll
            for (int msk = 16; msk >= 1; msk >>= 1)
                pu = fmaxf(pu, __shfl_xor(pu, msk, 64));
            resv[p] = pu;
        }
    }
    if (lane == 0)
        *(float4*)(out + pt0) = make_float4(resv[0], resv[1], resv[2], resv[3]);
}

// ---------------- host launch ----------------------------------------------
extern "C" void kernel_launch(void* const* d_in, const int* in_sizes, int n_in,
                              void* d_out, int out_size, void* d_ws, size_t ws_size,
                              hipStream_t stream)
{
    const float* pts  = (const float*)d_in[0];
    const float* pp   = (const float*)d_in[1];
    const float* iw   = (const float*)d_in[2];
    const float* uw   = (const float*)d_in[3];
    const int*   flag = (const int*)d_in[4];
    float* out = (float*)d_out;

    float*  ws_c   = (float*)d_ws;             // 32768 floats (128 KB)
    float*  params = ws_c + 32768;             // 2048 floats (8 KB)
    float2* st_ws  = (float2*)(params + 2048); // 128 float2 (1 KB)

    // control radians with host libm (matches CPython math module)
    Rad12 rad;
    const double th = M_PI * 2.0 / 16.0 + atan(tan(2.0 * M_PI / 16.0) / 3.0);
    for (int i = 0; i < 4; ++i) {
        double base = 2.0 * M_PI / 4.0 * (double)i;
        rad.v[3 * i + 0] = (float)base;
        rad.v[3 * i + 1] = (float)(base + th);
        rad.v[3 * i + 2] = (float)(2.0 * M_PI / 4.0 * (double)(i + 1) - th);
    }

    curve_prep<<<64, 256, 0, stream>>>(pp, iw, rad, ws_c, params, st_ws);
    csg_main<<<Bb * Mm / 32, 512, 0, stream>>>(pts, iw, uw, flag,
                                               ws_c, params, st_ws, out);
}

// Round 11
// 331.698 us; speedup vs baseline: 1.1528x; 1.1528x over previous
//
#include <hip/hip_runtime.h>
#include <math.h>

#define Bb 4
#define Mm 8192
#define Kk 64
#define Cc 32
#define Pp 28

#define OFF_PSDF  (Bb*Mm)                          // 32768
#define OFF_INTER (Bb*Mm + Bb*Mm*Kk)               // 2129920
#define OFF_SD    (Bb*Mm + Bb*Mm*Kk + Bb*Mm*Cc)    // 3178496

#define W40    57.707801635558535f      // 40*log2(e)
#define NL2_40 (-0.017328679513998632f) // -ln2/40
#define S75    108.20212806667225f      // 75*log2(e)
#define EPS_OCC 1e-6f

struct Rad12 { float v[12]; };

__device__ __forceinline__ float fexp2(float x){ return __builtin_amdgcn_exp2f(x); }
__device__ __forceinline__ float frcp(float x){ return __builtin_amdgcn_rcpf(x); }

// ---------------- Kernel 0: expand curves + params + (k,c) sums ------------
// thread g -> k = g&63 (coalesced), n = (g>>6)&63, b = g>>12
// ws_c [b][j=n>>1][k][4] = {m2x_e, m2x_o, m2y_e, m2y_o}
__global__ __launch_bounds__(256)
void curve_prep(const float* __restrict__ pp, const float* __restrict__ iw_g,
                Rad12 rad,
                float* __restrict__ ws_c, float* __restrict__ params_ws,
                float2* __restrict__ st_ws)
{
    const int g = blockIdx.x * 256 + threadIdx.x;   // 16384 threads
    const int k = g & 63;
    const int n = (g >> 6) & 63;
    const int b = g >> 12;

#define PP(p) pp[((b * Pp) + (p)) * Kk + k]

    const int s  = n >> 4;
    const int it = n & 15;
    const float t = (float)it * 0.0625f;            // exact i/16
    const int s1 = (s + 1) & 3;

    float r0 = fabsf(PP(8 + 3 * s + 0));
    float r1 = fabsf(PP(8 + 3 * s + 1));
    float r2 = fabsf(PP(8 + 3 * s + 2));
    float r3 = fabsf(PP(8 + 3 * s1 + 0));
    float w1 = fabsf(PP(20 + 2 * s + 0));
    float w2 = fabsf(PP(20 + 2 * s + 1));

    float a0 = rad.v[3 * s + 0], a1 = rad.v[3 * s + 1];
    float a2 = rad.v[3 * s + 2], a3 = rad.v[3 * s1 + 0];

    float P0x = cosf(a0) * r0, P0y = sinf(a0) * r0;
    float P1x = cosf(a1) * r1, P1y = sinf(a1) * r1;
    float P2x = cosf(a2) * r2, P2y = sinf(a2) * r2;
    float P3x = cosf(a3) * r3, P3y = sinf(a3) * r3;

    float omt = 1.0f - t;
    float b0 = omt * omt * omt;
    float b1 = (3.0f * t) * (omt * omt);
    float b2 = (3.0f * (t * t)) * omt;
    float b3 = t * t * t;
    float bw1 = b1 * w1, bw2 = b2 * w2;
    float den = ((b0 + bw1) + bw2) + b3;
    float nx  = ((b0 * P0x + bw1 * P1x) + bw2 * P2x) + b3 * P3x;
    float ny  = ((b0 * P0y + bw1 * P1y) + bw2 * P2y) + b3 * P3y;

    float cx = nx / den, cy = ny / den;
    const int j = n >> 1, h = n & 1;
    float* base = ws_c + (((b * 32 + j) * 64) + k) * 4;
    base[h]     = -2.0f * cx;
    base[2 + h] = -2.0f * cy;

    if (n < 8) {
        float val;
        if (n < 4) {
            float q0 = PP(0), q1 = PP(1), q2 = PP(2), q3 = PP(3);
            float nrm = sqrtf(q0 * q0 + q1 * q1 + q2 * q2 + q3 * q3);
            val = PP(n) / nrm;
        } else {
            val = PP(n);        // p=4..6 trans, p=7 height
        }
        params_ws[(b * Kk + k) * 8 + n] = val;
    }
#undef PP

    // fold-in: per-(b,c) saturated-occ softmin sums S0,T0
    if (blockIdx.x == 0 && threadIdx.x < 128) {
        const int tb = threadIdx.x >> 5, tc = threadIdx.x & 31;
        float S = 0.0f, T = 0.0f;
        for (int kk = 0; kk < 64; ++kk) {
            float w   = iw_g[tb * 2048 + kk * 32 + tc];
            float b40 = (w - 1.0f) * W40;
            float e   = fexp2(b40);
            S += e;
            T  = fmaf(e, b40, T);
        }
        st_ws[threadIdx.x] = make_float2(S, T);
    }
}

// ---------------- Kernel 1: fused main ------------------------------------
// block = 512 threads = 8 waves; each wave = 4 points (ph1 lane = primitive k).
// __launch_bounds__(512,4): VGPR cap 128 — R9/R10's (512,8) cap=64 caused
// catastrophic scratch spill (862 MB writes). LDS 33 KB allows 4 blocks/CU
// when natural VGPR alloc <= 64 (R8 measured 40).
//   ph1: [0,8192) curve quads [j][k][4]   (csq recomputed in-register, 4x-scaled)
//   ph2 (aliased after barrier): [0,2048) occ [ptl][k];
//        [2048,6144) float2 {a,b} tables [k][c]
//   [8192,8256) S0T0 float2[c]  (non-aliased)
__global__ __launch_bounds__(512, 4)
void csg_main(const float* __restrict__ pts, const float* __restrict__ iw_g,
              const float* __restrict__ uw_g, const int* __restrict__ flag,
              const float* __restrict__ ws_c, const float* __restrict__ params_ws,
              const float2* __restrict__ st_ws, float* __restrict__ out)
{
    __shared__ __align__(16) float s_pool[8256];

    const int tid = threadIdx.x;
    const int bid = blockIdx.x;
    const int b   = bid >> 8;                  // 256 blocks per batch
    const int m0  = (bid & 255) << 5;          // 32 points per block

    // ---- stage LDS (curve quads) + iw into regs ----
    float wreg[4];
    {
        const float4* cs = (const float4*)(ws_c + (size_t)b * 8192);
        float4* cd = (float4*)s_pool;
#pragma unroll
        for (int i = 0; i < 4; ++i) cd[tid + i * 512] = cs[tid + i * 512];
#pragma unroll
        for (int i = 0; i < 4; ++i) wreg[i] = iw_g[b * 2048 + tid + i * 512];
        if (tid < 32) ((float2*)&s_pool[8192])[tid] = st_ws[b * 32 + tid];
    }
    __syncthreads();

    const int wid  = tid >> 6;
    const int lane = tid & 63;
    const int k    = lane;
    const int pt0  = b * Mm + m0 + (wid << 2);   // 4 pts per wave

    const float4* prm4 = (const float4*)(params_ws + ((b << 6) + k) * 8);
    float4 q4 = prm4[0];   // qw qx qy qz (normalized)
    float4 t4 = prm4[1];   // tx ty tz height

    const float4* pts4 = (const float4*)(pts + (size_t)pt0 * 3);
    float4 A = pts4[0], Bv = pts4[1], Cv = pts4[2];
    float pxs[4] = {A.x, A.w, Bv.z, Cv.y};
    float pys[4] = {A.y, Bv.x, Bv.w, Cv.z};
    float pzs[4] = {A.z, Bv.y, Cv.x, Cv.w};

    float px4[4], py4[4], plzv[4], psq[4];
    {
        float vx = -q4.y, vy = -q4.z, vz = -q4.w, qw = q4.x;
#pragma unroll
        for (int p = 0; p < 4; ++p) {
            float px = pxs[p] - t4.x, py = pys[p] - t4.y, pz = pzs[p] - t4.z;
            float t1x = 2.0f * (vy * pz - vz * py);
            float t1y = 2.0f * (vz * px - vx * pz);
            float t1z = 2.0f * (vx * py - vy * px);
            float plx = px + qw * t1x + (vy * t1z - vz * t1y);
            float ply = py + qw * t1y + (vz * t1x - vx * t1z);
            plzv[p] = pz + qw * t1z + (vx * t1y - vy * t1x);
            psq[p]  = plx * plx + ply * ply;
            px4[p]  = 4.0f * plx;                 // exact pow2 scale
            py4[p]  = 4.0f * ply;
        }
    }

    // 4x-scaled: cq4 = 4*csq = fma(m2x,m2x,m2y^2) exact;
    // d4 = 4*(csq - 2*dot) = fma(m2x, 4px, fma(m2y, 4py, cq4)) exact.
    // strict-< argmin identical; d2 = psq + 0.25*best4 exact.
    float best4[4] = {1e30f, 1e30f, 1e30f, 1e30f};
    float bcsq4[4] = {0.0f, 0.0f, 0.0f, 0.0f};
    {
        const float4* cdp = (const float4*)&s_pool[k * 4];   // j*1024B imm
#pragma unroll
        for (int j = 0; j < 32; ++j) {
            float4 cd = cdp[j * 64];       // {m2x_e, m2x_o, m2y_e, m2y_o}
            float cq4x = fmaf(cd.x, cd.x, cd.z * cd.z);
            float cq4y = fmaf(cd.y, cd.y, cd.w * cd.w);
#pragma unroll
            for (int p = 0; p < 4; ++p) {
                float da = fmaf(cd.x, px4[p], fmaf(cd.z, py4[p], cq4x));
                if (da < best4[p]) { best4[p] = da; bcsq4[p] = cq4x; }
                float db = fmaf(cd.y, px4[p], fmaf(cd.w, py4[p], cq4y));
                if (db < best4[p]) { best4[p] = db; bcsq4[p] = cq4y; }
            }
        }
    }

    float occ[4];
    unsigned long long mask[4];
#pragma unroll
    for (int p = 0; p < 4; ++p) {
        float d2    = psq[p] + 0.25f * best4[p];        // == psq + best exact
        float bq    = 0.25f * bcsq4[p];                 // == bcsq exact
        float ud    = sqrtf(fmaxf(d2, 0.0f) + 1e-12f);
        float sgn   = (psq[p] <= bq) ? -1.0f : 1.0f;    // == sqrt-compare
        float sdf2d = sgn * ud;
        float dzv   = fabsf(plzv[p]) - t4.w;
        float inner = fminf(fmaxf(sdf2d, dzv), 0.0f);
        float r1m   = fmaxf(sdf2d, 0.0f), r2m = fmaxf(dzv, 0.0f);
        float psdf  = inner + sqrtf(r1m * r1m + r2m * r2m + 1e-12f);
        out[OFF_PSDF + (pt0 + p) * Kk + k] = psdf;
        out[OFF_SD   + (pt0 + p) * Kk + k] = ud;
        occ[p]  = frcp(1.0f + fexp2(S75 * psdf));   // sigmoid(-75*psdf)
        mask[p] = __ballot(occ[p] > EPS_OCC);
    }

    // ---- barrier: curve LDS dead; build ph2 tables ----
    __syncthreads();
    {
        const int ptl = wid << 2;
#pragma unroll
        for (int p = 0; p < 4; ++p)
            s_pool[(ptl + p) * 64 + k] = occ[p];
#pragma unroll
        for (int i = 0; i < 4; ++i) {
            int idx = tid + i * 512;               // (k,c) = idx>>5, idx&31
            float w = wreg[i];
            ((float2*)&s_pool[2048])[idx] = make_float2(w * (-W40), (w - 1.0f) * W40);
        }
    }
    __syncthreads();

    // ================= Phase 2: lane = c (duplicated across halves) ========
    const int training = flag[0];
    const int c = lane & 31;
    const float2* tbl = (const float2*)&s_pool[2048];

    float inter[4];
    if (training) {
        float2 s0t0 = ((const float2*)&s_pool[8192])[c];
#pragma unroll
        for (int p = 0; p < 4; ++p) {
            unsigned long long m = mask[p];
            const int ptl = (wid << 2) + p;
            float sw = s0t0.x, swp = s0t0.y;
            while (m) {
                int kk = __builtin_ctzll(m); m &= m - 1;
                float osv = s_pool[ptl * 64 + kk];          // broadcast
                float2 wv = tbl[kk * 32 + c];               // {a, b}
                float pre = fmaf(wv.x, osv, wv.y);          // -40*log2e*pre_i
                float e   = fexp2(pre);                     // in (0,1]: safe
                float e0  = fexp2(wv.y);                    // saturated term
                sw  += (e - e0);
                swp += fmaf(e, pre, -(e0 * wv.y));
            }
            inter[p] = swp * frcp(sw) * NL2_40;
        }
    } else {
#pragma unroll
        for (int p = 0; p < 4; ++p) {
            const int ptl = (wid << 2) + p;
            float mx = -1e30f;
            for (int kk = 0; kk < 64; ++kk) {
                float osv = s_pool[ptl * 64 + kk];
                float2 wv = tbl[kk * 32 + c];
                mx = fmaxf(mx, fmaf(wv.x, osv, wv.y));
            }
            inter[p] = mx * NL2_40;                 // min_k pre_i
        }
    }

    if (lane < Cc) {
#pragma unroll
        for (int p = 0; p < 4; ++p)
            out[OFF_INTER + (pt0 + p) * Cc + c] = inter[p];
    }

    // ---- union over c (softmax / max) ----
    float uwv = uw_g[b * Cc + c];
    float resv[4];
    if (training) {
#pragma unroll
        for (int p = 0; p < 4; ++p) {
            float pu  = uwv * inter[p];
            float e   = fexp2(W40 * pu);             // exp(40*pre_u) <= e^40
            float num = e * pu, den = e;
#pragma unroll
            for (int msk = 16; msk >= 1; msk >>= 1) {
                num += __shfl_xor(num, msk, 64);
                den += __shfl_xor(den, msk, 64);
            }
            resv[p] = num * frcp(den);
        }
    } else {
#pragma unroll
        for (int p = 0; p < 4; ++p) {
            float pu = uwv * inter[p];
#pragma unroll
            for (int msk = 16; msk >= 1; msk >>= 1)
                pu = fmaxf(pu, __shfl_xor(pu, msk, 64));
            resv[p] = pu;
        }
    }
    if (lane == 0)
        *(float4*)(out + pt0) = make_float4(resv[0], resv[1], resv[2], resv[3]);
}

// ---------------- host launch ----------------------------------------------
extern "C" void kernel_launch(void* const* d_in, const int* in_sizes, int n_in,
                              void* d_out, int out_size, void* d_ws, size_t ws_size,
                              hipStream_t stream)
{
    const float* pts  = (const float*)d_in[0];
    const float* pp   = (const float*)d_in[1];
    const float* iw   = (const float*)d_in[2];
    const float* uw   = (const float*)d_in[3];
    const int*   flag = (const int*)d_in[4];
    float* out = (float*)d_out;

    float*  ws_c   = (float*)d_ws;             // 32768 floats (128 KB)
    float*  params = ws_c + 32768;             // 2048 floats (8 KB)
    float2* st_ws  = (float2*)(params + 2048); // 128 float2 (1 KB)

    // control radians with host libm (matches CPython math module)
    Rad12 rad;
    const double th = M_PI * 2.0 / 16.0 + atan(tan(2.0 * M_PI / 16.0) / 3.0);
    for (int i = 0; i < 4; ++i) {
        double base = 2.0 * M_PI / 4.0 * (double)i;
        rad.v[3 * i + 0] = (float)base;
        rad.v[3 * i + 1] = (float)(base + th);
        rad.v[3 * i + 2] = (float)(2.0 * M_PI / 4.0 * (double)(i + 1) - th);
    }

    curve_prep<<<64, 256, 0, stream>>>(pp, iw, rad, ws_c, params, st_ws);
    csg_main<<<Bb * Mm / 32, 512, 0, stream>>>(pts, iw, uw, flag,
                                               ws_c, params, st_ws, out);
}

// Round 12
// 40.742 us; speedup vs baseline: 9.3858x; 8.1415x over previous
//
#include <hip/hip_runtime.h>
#include <math.h>

#define Bb 4
#define Mm 8192
#define Kk 64
#define Cc 32
#define Pp 28

#define OFF_PSDF  (Bb*Mm)                          // 32768
#define OFF_INTER (Bb*Mm + Bb*Mm*Kk)               // 2129920
#define OFF_SD    (Bb*Mm + Bb*Mm*Kk + Bb*Mm*Cc)    // 3178496

#define W40    57.707801635558535f      // 40*log2(e)
#define NL2_40 (-0.017328679513998632f) // -ln2/40
#define S75    108.20212806667225f      // 75*log2(e)
#define EPS_OCC 1e-6f

struct Rad12 { float v[12]; };

__device__ __forceinline__ float fexp2(float x){ return __builtin_amdgcn_exp2f(x); }
__device__ __forceinline__ float frcp(float x){ return __builtin_amdgcn_rcpf(x); }

// ---------------- Kernel 0: expand curves + params + (k,c) sums ------------
// thread g -> k = g&63 (coalesced), n = (g>>6)&63, b = g>>12
// ws_c [b][j=n>>1][k][4] = {m2x_e, m2x_o, m2y_e, m2y_o}
__global__ __launch_bounds__(256)
void curve_prep(const float* __restrict__ pp, const float* __restrict__ iw_g,
                Rad12 rad,
                float* __restrict__ ws_c, float* __restrict__ params_ws,
                float2* __restrict__ st_ws)
{
    const int g = blockIdx.x * 256 + threadIdx.x;   // 16384 threads
    const int k = g & 63;
    const int n = (g >> 6) & 63;
    const int b = g >> 12;

#define PP(p) pp[((b * Pp) + (p)) * Kk + k]

    const int s  = n >> 4;
    const int it = n & 15;
    const float t = (float)it * 0.0625f;            // exact i/16
    const int s1 = (s + 1) & 3;

    float r0 = fabsf(PP(8 + 3 * s + 0));
    float r1 = fabsf(PP(8 + 3 * s + 1));
    float r2 = fabsf(PP(8 + 3 * s + 2));
    float r3 = fabsf(PP(8 + 3 * s1 + 0));
    float w1 = fabsf(PP(20 + 2 * s + 0));
    float w2 = fabsf(PP(20 + 2 * s + 1));

    float a0 = rad.v[3 * s + 0], a1 = rad.v[3 * s + 1];
    float a2 = rad.v[3 * s + 2], a3 = rad.v[3 * s1 + 0];

    float P0x = cosf(a0) * r0, P0y = sinf(a0) * r0;
    float P1x = cosf(a1) * r1, P1y = sinf(a1) * r1;
    float P2x = cosf(a2) * r2, P2y = sinf(a2) * r2;
    float P3x = cosf(a3) * r3, P3y = sinf(a3) * r3;

    float omt = 1.0f - t;
    float b0 = omt * omt * omt;
    float b1 = (3.0f * t) * (omt * omt);
    float b2 = (3.0f * (t * t)) * omt;
    float b3 = t * t * t;
    float bw1 = b1 * w1, bw2 = b2 * w2;
    float den = ((b0 + bw1) + bw2) + b3;
    float nx  = ((b0 * P0x + bw1 * P1x) + bw2 * P2x) + b3 * P3x;
    float ny  = ((b0 * P0y + bw1 * P1y) + bw2 * P2y) + b3 * P3y;

    float cx = nx / den, cy = ny / den;
    const int j = n >> 1, h = n & 1;
    float* base = ws_c + (((b * 32 + j) * 64) + k) * 4;
    base[h]     = -2.0f * cx;
    base[2 + h] = -2.0f * cy;

    if (n < 8) {
        float val;
        if (n < 4) {
            float q0 = PP(0), q1 = PP(1), q2 = PP(2), q3 = PP(3);
            float nrm = sqrtf(q0 * q0 + q1 * q1 + q2 * q2 + q3 * q3);
            val = PP(n) / nrm;
        } else {
            val = PP(n);        // p=4..6 trans, p=7 height
        }
        params_ws[(b * Kk + k) * 8 + n] = val;
    }
#undef PP

    // fold-in: per-(b,c) saturated-occ softmin sums S0,T0
    if (blockIdx.x == 0 && threadIdx.x < 128) {
        const int tb = threadIdx.x >> 5, tc = threadIdx.x & 31;
        float S = 0.0f, T = 0.0f;
        for (int kk = 0; kk < 64; ++kk) {
            float w   = iw_g[tb * 2048 + kk * 32 + tc];
            float b40 = (w - 1.0f) * W40;
            float e   = fexp2(b40);
            S += e;
            T  = fmaf(e, b40, T);
        }
        st_ws[threadIdx.x] = make_float2(S, T);
    }
}

// ---------------- Kernel 1: fused main ------------------------------------
// block = 512 threads = 8 waves; each wave = 4 points (ph1 lane = primitive k).
// NO min-waves arg: R9-R11 showed caps (64/128) make the RA spill ~1-2 KB per
// thread (674-862 MB scratch traffic) because the full j-loop unroll hoists
// all 32 ds_reads. unroll 8 bounds the in-flight loads; cap 256 never spills.
//   ph1: [0,8192) curve quads [j][k][4]   (csq recomputed in-register, 4x-scaled)
//   ph2 (aliased after barrier): [0,2048) occ [ptl][k];
//        [2048,6144) float2 {a,b} tables [k][c]
//   [8192,8256) S0T0 float2[c]  (non-aliased)
__global__ __launch_bounds__(512)
void csg_main(const float* __restrict__ pts, const float* __restrict__ iw_g,
              const float* __restrict__ uw_g, const int* __restrict__ flag,
              const float* __restrict__ ws_c, const float* __restrict__ params_ws,
              const float2* __restrict__ st_ws, float* __restrict__ out)
{
    __shared__ __align__(16) float s_pool[8256];

    const int tid = threadIdx.x;
    const int bid = blockIdx.x;
    const int b   = bid >> 8;                  // 256 blocks per batch
    const int m0  = (bid & 255) << 5;          // 32 points per block

    // ---- stage LDS (curve quads) + iw into regs ----
    float wreg[4];
    {
        const float4* cs = (const float4*)(ws_c + (size_t)b * 8192);
        float4* cd = (float4*)s_pool;
#pragma unroll
        for (int i = 0; i < 4; ++i) cd[tid + i * 512] = cs[tid + i * 512];
#pragma unroll
        for (int i = 0; i < 4; ++i) wreg[i] = iw_g[b * 2048 + tid + i * 512];
        if (tid < 32) ((float2*)&s_pool[8192])[tid] = st_ws[b * 32 + tid];
    }
    __syncthreads();

    const int wid  = tid >> 6;
    const int lane = tid & 63;
    const int k    = lane;
    const int pt0  = b * Mm + m0 + (wid << 2);   // 4 pts per wave

    const float4* prm4 = (const float4*)(params_ws + ((b << 6) + k) * 8);
    float4 q4 = prm4[0];   // qw qx qy qz (normalized)
    float4 t4 = prm4[1];   // tx ty tz height

    const float4* pts4 = (const float4*)(pts + (size_t)pt0 * 3);
    float4 A = pts4[0], Bv = pts4[1], Cv = pts4[2];
    float pxs[4] = {A.x, A.w, Bv.z, Cv.y};
    float pys[4] = {A.y, Bv.x, Bv.w, Cv.z};
    float pzs[4] = {A.z, Bv.y, Cv.x, Cv.w};

    float px4[4], py4[4], plzv[4], psq[4];
    {
        float vx = -q4.y, vy = -q4.z, vz = -q4.w, qw = q4.x;
#pragma unroll
        for (int p = 0; p < 4; ++p) {
            float px = pxs[p] - t4.x, py = pys[p] - t4.y, pz = pzs[p] - t4.z;
            float t1x = 2.0f * (vy * pz - vz * py);
            float t1y = 2.0f * (vz * px - vx * pz);
            float t1z = 2.0f * (vx * py - vy * px);
            float plx = px + qw * t1x + (vy * t1z - vz * t1y);
            float ply = py + qw * t1y + (vz * t1x - vx * t1z);
            plzv[p] = pz + qw * t1z + (vx * t1y - vy * t1x);
            psq[p]  = plx * plx + ply * ply;
            px4[p]  = 4.0f * plx;                 // exact pow2 scale
            py4[p]  = 4.0f * ply;
        }
    }

    // 4x-scaled: cq4 = 4*csq = fma(m2x,m2x,m2y^2) exact;
    // d4 = 4*(csq - 2*dot) = fma(m2x, 4px, fma(m2y, 4py, cq4)) exact.
    // strict-< argmin identical; d2 = psq + 0.25*best4 exact.
    float best4[4] = {1e30f, 1e30f, 1e30f, 1e30f};
    float bcsq4[4] = {0.0f, 0.0f, 0.0f, 0.0f};
    {
        const float4* cdp = (const float4*)&s_pool[k * 4];   // j*1024B imm
#pragma unroll 8
        for (int j = 0; j < 32; ++j) {
            float4 cd = cdp[j * 64];       // {m2x_e, m2x_o, m2y_e, m2y_o}
            float cq4x = fmaf(cd.x, cd.x, cd.z * cd.z);
            float cq4y = fmaf(cd.y, cd.y, cd.w * cd.w);
#pragma unroll
            for (int p = 0; p < 4; ++p) {
                float da = fmaf(cd.x, px4[p], fmaf(cd.z, py4[p], cq4x));
                if (da < best4[p]) { best4[p] = da; bcsq4[p] = cq4x; }
                float db = fmaf(cd.y, px4[p], fmaf(cd.w, py4[p], cq4y));
                if (db < best4[p]) { best4[p] = db; bcsq4[p] = cq4y; }
            }
        }
    }

    float occ[4];
    unsigned long long mask[4];
#pragma unroll
    for (int p = 0; p < 4; ++p) {
        float d2    = psq[p] + 0.25f * best4[p];        // == psq + best exact
        float bq    = 0.25f * bcsq4[p];                 // == bcsq exact
        float ud    = sqrtf(fmaxf(d2, 0.0f) + 1e-12f);
        float sgn   = (psq[p] <= bq) ? -1.0f : 1.0f;    // == sqrt-compare
        float sdf2d = sgn * ud;
        float dzv   = fabsf(plzv[p]) - t4.w;
        float inner = fminf(fmaxf(sdf2d, dzv), 0.0f);
        float r1m   = fmaxf(sdf2d, 0.0f), r2m = fmaxf(dzv, 0.0f);
        float psdf  = inner + sqrtf(r1m * r1m + r2m * r2m + 1e-12f);
        out[OFF_PSDF + (pt0 + p) * Kk + k] = psdf;
        out[OFF_SD   + (pt0 + p) * Kk + k] = ud;
        occ[p]  = frcp(1.0f + fexp2(S75 * psdf));   // sigmoid(-75*psdf)
        mask[p] = __ballot(occ[p] > EPS_OCC);
    }

    // ---- barrier: curve LDS dead; build ph2 tables ----
    __syncthreads();
    {
        const int ptl = wid << 2;
#pragma unroll
        for (int p = 0; p < 4; ++p)
            s_pool[(ptl + p) * 64 + k] = occ[p];
#pragma unroll
        for (int i = 0; i < 4; ++i) {
            int idx = tid + i * 512;               // (k,c) = idx>>5, idx&31
            float w = wreg[i];
            ((float2*)&s_pool[2048])[idx] = make_float2(w * (-W40), (w - 1.0f) * W40);
        }
    }
    __syncthreads();

    // ================= Phase 2: lane = c (duplicated across halves) ========
    const int training = flag[0];
    const int c = lane & 31;
    const float2* tbl = (const float2*)&s_pool[2048];

    float inter[4];
    if (training) {
        float2 s0t0 = ((const float2*)&s_pool[8192])[c];
#pragma unroll
        for (int p = 0; p < 4; ++p) {
            unsigned long long m = mask[p];
            const int ptl = (wid << 2) + p;
            float sw = s0t0.x, swp = s0t0.y;
            while (m) {
                int kk = __builtin_ctzll(m); m &= m - 1;
                float osv = s_pool[ptl * 64 + kk];          // broadcast
                float2 wv = tbl[kk * 32 + c];               // {a, b}
                float pre = fmaf(wv.x, osv, wv.y);          // -40*log2e*pre_i
                float e   = fexp2(pre);                     // in (0,1]: safe
                float e0  = fexp2(wv.y);                    // saturated term
                sw  += (e - e0);
                swp += fmaf(e, pre, -(e0 * wv.y));
            }
            inter[p] = swp * frcp(sw) * NL2_40;
        }
    } else {
#pragma unroll
        for (int p = 0; p < 4; ++p) {
            const int ptl = (wid << 2) + p;
            float mx = -1e30f;
#pragma unroll 8
            for (int kk = 0; kk < 64; ++kk) {
                float osv = s_pool[ptl * 64 + kk];
                float2 wv = tbl[kk * 32 + c];
                mx = fmaxf(mx, fmaf(wv.x, osv, wv.y));
            }
            inter[p] = mx * NL2_40;                 // min_k pre_i
        }
    }

    if (lane < Cc) {
#pragma unroll
        for (int p = 0; p < 4; ++p)
            out[OFF_INTER + (pt0 + p) * Cc + c] = inter[p];
    }

    // ---- union over c (softmax / max) ----
    float uwv = uw_g[b * Cc + c];
    float resv[4];
    if (training) {
#pragma unroll
        for (int p = 0; p < 4; ++p) {
            float pu  = uwv * inter[p];
            float e   = fexp2(W40 * pu);             // exp(40*pre_u) <= e^40
            float num = e * pu, den = e;
#pragma unroll
            for (int msk = 16; msk >= 1; msk >>= 1) {
                num += __shfl_xor(num, msk, 64);
                den += __shfl_xor(den, msk, 64);
            }
            resv[p] = num * frcp(den);
        }
    } else {
#pragma unroll
        for (int p = 0; p < 4; ++p) {
            float pu = uwv * inter[p];
#pragma unroll
            for (int msk = 16; msk >= 1; msk >>= 1)
                pu = fmaxf(pu, __shfl_xor(pu, msk, 64));
            resv[p] = pu;
        }
    }
    if (lane == 0)
        *(float4*)(out + pt0) = make_float4(resv[0], resv[1], resv[2], resv[3]);
}

// ---------------- host launch ----------------------------------------------
extern "C" void kernel_launch(void* const* d_in, const int* in_sizes, int n_in,
                              void* d_out, int out_size, void* d_ws, size_t ws_size,
                              hipStream_t stream)
{
    const float* pts  = (const float*)d_in[0];
    const float* pp   = (const float*)d_in[1];
    const float* iw   = (const float*)d_in[2];
    const float* uw   = (const float*)d_in[3];
    const int*   flag = (const int*)d_in[4];
    float* out = (float*)d_out;

    float*  ws_c   = (float*)d_ws;             // 32768 floats (128 KB)
    float*  params = ws_c + 32768;             // 2048 floats (8 KB)
    float2* st_ws  = (float2*)(params + 2048); // 128 float2 (1 KB)

    // control radians with host libm (matches CPython math module)
    Rad12 rad;
    const double th = M_PI * 2.0 / 16.0 + atan(tan(2.0 * M_PI / 16.0) / 3.0);
    for (int i = 0; i < 4; ++i) {
        double base = 2.0 * M_PI / 4.0 * (double)i;
        rad.v[3 * i + 0] = (float)base;
        rad.v[3 * i + 1] = (float)(base + th);
        rad.v[3 * i + 2] = (float)(2.0 * M_PI / 4.0 * (double)(i + 1) - th);
    }

    curve_prep<<<64, 256, 0, stream>>>(pp, iw, rad, ws_c, params, st_ws);
    csg_main<<<Bb * Mm / 32, 512, 0, stream>>>(pts, iw, uw, flag,
                                               ws_c, params, st_ws, out);
}

// Round 13
// 40.344 us; speedup vs baseline: 9.4782x; 1.0099x over previous
//
#include <hip/hip_runtime.h>
#include <math.h>

#define Bb 4
#define Mm 8192
#define Kk 64
#define Cc 32
#define Pp 28

#define OFF_PSDF  (Bb*Mm)                          // 32768
#define OFF_INTER (Bb*Mm + Bb*Mm*Kk)               // 2129920
#define OFF_SD    (Bb*Mm + Bb*Mm*Kk + Bb*Mm*Cc)    // 3178496

#define W40    57.707801635558535f      // 40*log2(e)
#define NL2_40 (-0.017328679513998632f) // -ln2/40
#define S75    108.20212806667225f      // 75*log2(e)
#define EPS_OCC 1e-6f

struct Rad12 { float v[12]; };

__device__ __forceinline__ float fexp2(float x){ return __builtin_amdgcn_exp2f(x); }
__device__ __forceinline__ float frcp(float x){ return __builtin_amdgcn_rcpf(x); }

// ---------------- Kernel 0: expand curves + params + (k,c) sums ------------
// thread g -> k = g&63 (coalesced), n = (g>>6)&63, b = g>>12
// ws_c [b][j=n>>1][k][4] = {m2x_e, m2x_o, m2y_e, m2y_o}
__global__ __launch_bounds__(256)
void curve_prep(const float* __restrict__ pp, const float* __restrict__ iw_g,
                Rad12 rad,
                float* __restrict__ ws_c, float* __restrict__ params_ws,
                float2* __restrict__ st_ws)
{
    const int g = blockIdx.x * 256 + threadIdx.x;   // 16384 threads
    const int k = g & 63;
    const int n = (g >> 6) & 63;
    const int b = g >> 12;

#define PP(p) pp[((b * Pp) + (p)) * Kk + k]

    const int s  = n >> 4;
    const int it = n & 15;
    const float t = (float)it * 0.0625f;            // exact i/16
    const int s1 = (s + 1) & 3;

    float r0 = fabsf(PP(8 + 3 * s + 0));
    float r1 = fabsf(PP(8 + 3 * s + 1));
    float r2 = fabsf(PP(8 + 3 * s + 2));
    float r3 = fabsf(PP(8 + 3 * s1 + 0));
    float w1 = fabsf(PP(20 + 2 * s + 0));
    float w2 = fabsf(PP(20 + 2 * s + 1));

    float a0 = rad.v[3 * s + 0], a1 = rad.v[3 * s + 1];
    float a2 = rad.v[3 * s + 2], a3 = rad.v[3 * s1 + 0];

    float P0x = cosf(a0) * r0, P0y = sinf(a0) * r0;
    float P1x = cosf(a1) * r1, P1y = sinf(a1) * r1;
    float P2x = cosf(a2) * r2, P2y = sinf(a2) * r2;
    float P3x = cosf(a3) * r3, P3y = sinf(a3) * r3;

    float omt = 1.0f - t;
    float b0 = omt * omt * omt;
    float b1 = (3.0f * t) * (omt * omt);
    float b2 = (3.0f * (t * t)) * omt;
    float b3 = t * t * t;
    float bw1 = b1 * w1, bw2 = b2 * w2;
    float den = ((b0 + bw1) + bw2) + b3;
    float nx  = ((b0 * P0x + bw1 * P1x) + bw2 * P2x) + b3 * P3x;
    float ny  = ((b0 * P0y + bw1 * P1y) + bw2 * P2y) + b3 * P3y;

    float cx = nx / den, cy = ny / den;
    const int j = n >> 1, h = n & 1;
    float* base = ws_c + (((b * 32 + j) * 64) + k) * 4;
    base[h]     = -2.0f * cx;
    base[2 + h] = -2.0f * cy;

    if (n < 8) {
        float val;
        if (n < 4) {
            float q0 = PP(0), q1 = PP(1), q2 = PP(2), q3 = PP(3);
            float nrm = sqrtf(q0 * q0 + q1 * q1 + q2 * q2 + q3 * q3);
            val = PP(n) / nrm;
        } else {
            val = PP(n);        // p=4..6 trans, p=7 height
        }
        params_ws[(b * Kk + k) * 8 + n] = val;
    }
#undef PP

    // fold-in: per-(b,c) saturated-occ softmin sums S0,T0
    if (blockIdx.x == 0 && threadIdx.x < 128) {
        const int tb = threadIdx.x >> 5, tc = threadIdx.x & 31;
        float S = 0.0f, T = 0.0f;
        for (int kk = 0; kk < 64; ++kk) {
            float w   = iw_g[tb * 2048 + kk * 32 + tc];
            float b40 = (w - 1.0f) * W40;
            float e   = fexp2(b40);
            S += e;
            T  = fmaf(e, b40, T);
        }
        st_ws[threadIdx.x] = make_float2(S, T);
    }
}

// ---------------- Kernel 1: fused main ------------------------------------
// block = 512 threads = 8 waves; each wave = 4 points (ph1 lane = primitive k).
// LDS EXACTLY 32 KB -> with VGPR<=64: 4 blocks/CU, capacity 1024 = grid: ONE round.
// NO __launch_bounds__ min-waves arg: every cap attempt (R9-R11) caused RA
// scratch-spill storms (674-862 MB). unroll 4 bounds in-flight ds_read regs.
//   ph1: [0,8192) curve quads [j][k][4]   (csq recomputed in-register, 4x-scaled)
//   ph2 (aliased after barrier): [0,2048) occ [ptl][k];
//        [2048,6144) float2 {a,b} tables [k][c]   (S0T0 read from global/L2)
__global__ __launch_bounds__(512)
void csg_main(const float* __restrict__ pts, const float* __restrict__ iw_g,
              const float* __restrict__ uw_g, const int* __restrict__ flag,
              const float* __restrict__ ws_c, const float* __restrict__ params_ws,
              const float2* __restrict__ st_ws, float* __restrict__ out)
{
    __shared__ __align__(16) float s_pool[8192];   // 32 KB exactly

    const int tid = threadIdx.x;
    const int bid = blockIdx.x;
    const int b   = bid >> 8;                  // 256 blocks per batch
    const int m0  = (bid & 255) << 5;          // 32 points per block

    // ---- stage LDS (curve quads) + iw into regs ----
    float wreg[4];
    {
        const float4* cs = (const float4*)(ws_c + (size_t)b * 8192);
        float4* cd = (float4*)s_pool;
#pragma unroll
        for (int i = 0; i < 4; ++i) cd[tid + i * 512] = cs[tid + i * 512];
#pragma unroll
        for (int i = 0; i < 4; ++i) wreg[i] = iw_g[b * 2048 + tid + i * 512];
    }
    __syncthreads();

    const int wid  = tid >> 6;
    const int lane = tid & 63;
    const int k    = lane;
    const int pt0  = b * Mm + m0 + (wid << 2);   // 4 pts per wave

    const float4* prm4 = (const float4*)(params_ws + ((b << 6) + k) * 8);
    float4 q4 = prm4[0];   // qw qx qy qz (normalized)
    float4 t4 = prm4[1];   // tx ty tz height

    const float4* pts4 = (const float4*)(pts + (size_t)pt0 * 3);
    float4 A = pts4[0], Bv = pts4[1], Cv = pts4[2];
    float pxs[4] = {A.x, A.w, Bv.z, Cv.y};
    float pys[4] = {A.y, Bv.x, Bv.w, Cv.z};
    float pzs[4] = {A.z, Bv.y, Cv.x, Cv.w};

    float px4[4], py4[4], plzv[4], psq[4];
    {
        float vx = -q4.y, vy = -q4.z, vz = -q4.w, qw = q4.x;
#pragma unroll
        for (int p = 0; p < 4; ++p) {
            float px = pxs[p] - t4.x, py = pys[p] - t4.y, pz = pzs[p] - t4.z;
            float t1x = 2.0f * (vy * pz - vz * py);
            float t1y = 2.0f * (vz * px - vx * pz);
            float t1z = 2.0f * (vx * py - vy * px);
            float plx = px + qw * t1x + (vy * t1z - vz * t1y);
            float ply = py + qw * t1y + (vz * t1x - vx * t1z);
            plzv[p] = pz + qw * t1z + (vx * t1y - vy * t1x);
            psq[p]  = plx * plx + ply * ply;
            px4[p]  = 4.0f * plx;                 // exact pow2 scale
            py4[p]  = 4.0f * ply;
        }
    }

    // 4x-scaled: cq4 = 4*csq = fma(m2x,m2x,m2y^2) exact;
    // d4 = 4*(csq - 2*dot) = fma(m2x, 4px, fma(m2y, 4py, cq4)) exact.
    // strict-< argmin identical; d2 = psq + 0.25*best4 exact.
    float best4[4] = {1e30f, 1e30f, 1e30f, 1e30f};
    float bcsq4[4] = {0.0f, 0.0f, 0.0f, 0.0f};
    {
        const float4* cdp = (const float4*)&s_pool[k * 4];   // j*1024B imm
#pragma unroll 4
        for (int j = 0; j < 32; ++j) {
            float4 cd = cdp[j * 64];       // {m2x_e, m2x_o, m2y_e, m2y_o}
            float cq4x = fmaf(cd.x, cd.x, cd.z * cd.z);
            float cq4y = fmaf(cd.y, cd.y, cd.w * cd.w);
#pragma unroll
            for (int p = 0; p < 4; ++p) {
                float da = fmaf(cd.x, px4[p], fmaf(cd.z, py4[p], cq4x));
                if (da < best4[p]) { best4[p] = da; bcsq4[p] = cq4x; }
                float db = fmaf(cd.y, px4[p], fmaf(cd.w, py4[p], cq4y));
                if (db < best4[p]) { best4[p] = db; bcsq4[p] = cq4y; }
            }
        }
    }

    float occ[4];
    unsigned long long mask[4];
#pragma unroll
    for (int p = 0; p < 4; ++p) {
        float d2    = psq[p] + 0.25f * best4[p];        // == psq + best exact
        float bq    = 0.25f * bcsq4[p];                 // == bcsq exact
        float ud    = sqrtf(fmaxf(d2, 0.0f) + 1e-12f);
        float sgn   = (psq[p] <= bq) ? -1.0f : 1.0f;    // == sqrt-compare
        float sdf2d = sgn * ud;
        float dzv   = fabsf(plzv[p]) - t4.w;
        float inner = fminf(fmaxf(sdf2d, dzv), 0.0f);
        float r1m   = fmaxf(sdf2d, 0.0f), r2m = fmaxf(dzv, 0.0f);
        float psdf  = inner + sqrtf(r1m * r1m + r2m * r2m + 1e-12f);
        out[OFF_PSDF + (pt0 + p) * Kk + k] = psdf;
        out[OFF_SD   + (pt0 + p) * Kk + k] = ud;
        occ[p]  = frcp(1.0f + fexp2(S75 * psdf));   // sigmoid(-75*psdf)
        mask[p] = __ballot(occ[p] > EPS_OCC);
    }

    // S0T0 from global (L2): issue before the barrier so latency hides
    const int c = lane & 31;
    float2 s0t0 = st_ws[b * 32 + c];

    // ---- barrier: curve LDS dead; build ph2 tables ----
    __syncthreads();
    {
        const int ptl = wid << 2;
#pragma unroll
        for (int p = 0; p < 4; ++p)
            s_pool[(ptl + p) * 64 + k] = occ[p];
#pragma unroll
        for (int i = 0; i < 4; ++i) {
            int idx = tid + i * 512;               // (k,c) = idx>>5, idx&31
            float w = wreg[i];
            ((float2*)&s_pool[2048])[idx] = make_float2(w * (-W40), (w - 1.0f) * W40);
        }
    }
    __syncthreads();

    // ================= Phase 2: lane = c (duplicated across halves) ========
    const int training = flag[0];
    const float2* tbl = (const float2*)&s_pool[2048];

    float inter[4];
    if (training) {
#pragma unroll
        for (int p = 0; p < 4; ++p) {
            unsigned long long m = mask[p];
            const int ptl = (wid << 2) + p;
            float sw = s0t0.x, swp = s0t0.y;
            while (m) {
                int kk = __builtin_ctzll(m); m &= m - 1;
                float osv = s_pool[ptl * 64 + kk];          // broadcast
                float2 wv = tbl[kk * 32 + c];               // {a, b}
                float pre = fmaf(wv.x, osv, wv.y);          // -40*log2e*pre_i
                float e   = fexp2(pre);                     // in (0,1]: safe
                float e0  = fexp2(wv.y);                    // saturated term
                sw  += (e - e0);
                swp += fmaf(e, pre, -(e0 * wv.y));
            }
            inter[p] = swp * frcp(sw) * NL2_40;
        }
    } else {
#pragma unroll
        for (int p = 0; p < 4; ++p) {
            const int ptl = (wid << 2) + p;
            float mx = -1e30f;
#pragma unroll 8
            for (int kk = 0; kk < 64; ++kk) {
                float osv = s_pool[ptl * 64 + kk];
                float2 wv = tbl[kk * 32 + c];
                mx = fmaxf(mx, fmaf(wv.x, osv, wv.y));
            }
            inter[p] = mx * NL2_40;                 // min_k pre_i
        }
    }

    if (lane < Cc) {
#pragma unroll
        for (int p = 0; p < 4; ++p)
            out[OFF_INTER + (pt0 + p) * Cc + c] = inter[p];
    }

    // ---- union over c (softmax / max) ----
    float uwv = uw_g[b * Cc + c];
    float resv[4];
    if (training) {
#pragma unroll
        for (int p = 0; p < 4; ++p) {
            float pu  = uwv * inter[p];
            float e   = fexp2(W40 * pu);             // exp(40*pre_u) <= e^40
            float num = e * pu, den = e;
#pragma unroll
            for (int msk = 16; msk >= 1; msk >>= 1) {
                num += __shfl_xor(num, msk, 64);
                den += __shfl_xor(den, msk, 64);
            }
            resv[p] = num * frcp(den);
        }
    } else {
#pragma unroll
        for (int p = 0; p < 4; ++p) {
            float pu = uwv * inter[p];
#pragma unroll
            for (int msk = 16; msk >= 1; msk >>= 1)
                pu = fmaxf(pu, __shfl_xor(pu, msk, 64));
            resv[p] = pu;
        }
    }
    if (lane == 0)
        *(float4*)(out + pt0) = make_float4(resv[0], resv[1], resv[2], resv[3]);
}

// ---------------- host launch ----------------------------------------------
extern "C" void kernel_launch(void* const* d_in, const int* in_sizes, int n_in,
                              void* d_out, int out_size, void* d_ws, size_t ws_size,
                              hipStream_t stream)
{
    const float* pts  = (const float*)d_in[0];
    const float* pp   = (const float*)d_in[1];
    const float* iw   = (const float*)d_in[2];
    const float* uw   = (const float*)d_in[3];
    const int*   flag = (const int*)d_in[4];
    float* out = (float*)d_out;

    float*  ws_c   = (float*)d_ws;             // 32768 floats (128 KB)
    float*  params = ws_c + 32768;             // 2048 floats (8 KB)
    float2* st_ws  = (float2*)(params + 2048); // 128 float2 (1 KB)

    // control radians with host libm (matches CPython math module)
    Rad12 rad;
    const double th = M_PI * 2.0 / 16.0 + atan(tan(2.0 * M_PI / 16.0) / 3.0);
    for (int i = 0; i < 4; ++i) {
        double base = 2.0 * M_PI / 4.0 * (double)i;
        rad.v[3 * i + 0] = (float)base;
        rad.v[3 * i + 1] = (float)(base + th);
        rad.v[3 * i + 2] = (float)(2.0 * M_PI / 4.0 * (double)(i + 1) - th);
    }

    curve_prep<<<64, 256, 0, stream>>>(pp, iw, rad, ws_c, params, st_ws);
    csg_main<<<Bb * Mm / 32, 512, 0, stream>>>(pts, iw, uw, flag,
                                               ws_c, params, st_ws, out);
}